// Round 4
// baseline (2060.316 us; speedup 1.0000x reference)
//
#include <hip/hip_runtime.h>
#include <math.h>

#define DD 48
#define HH 64
#define WW 128
#define VOL (DD*HH*WW)   // 393216
#define NC 64

typedef __attribute__((ext_vector_type(8))) short bf16x8;
typedef __attribute__((ext_vector_type(4))) float f32x4;
typedef __attribute__((ext_vector_type(4))) unsigned int u32x4v;
typedef __attribute__((ext_vector_type(2))) unsigned int u32x2v;

__device__ __forceinline__ float bflo(unsigned int u){
    union { unsigned int i; float f; } x; x.i = u<<16; return x.f; }
__device__ __forceinline__ float bfhi(unsigned int u){
    union { unsigned int i; float f; } x; x.i = u & 0xffff0000u; return x.f; }
__device__ __forceinline__ float bf2f(unsigned short u){
    union { unsigned int i; float f; } x; x.i = ((unsigned int)u)<<16; return x.f; }
__device__ __forceinline__ unsigned short f2bf(float f){
    union { float f; unsigned int i; } x; x.f = f;
    unsigned int i = x.i;
    return (unsigned short)((i + 0x7fffu + ((i>>16)&1u)) >> 16);  // RNE
}

// ================= weight prep =================

// src [co=64][ci=64][k=27] fp32 -> dst [k=27][co=64][ci=64] bf16
__global__ void k_wprep3(const float* __restrict__ src, unsigned short* __restrict__ dst){
    int idx = blockIdx.x*256 + threadIdx.x;
    if (idx >= 27*64*64) return;
    int ci = idx & 63; int t = idx >> 6; int co = t & 63; int k = t >> 6;
    dst[idx] = f2bf(src[(co*64+ci)*27 + k]);
}

// src [co][ci] fp32 -> dst [co][ci] bf16 (elementwise convert)
__global__ void k_wprep1(const float* __restrict__ src, unsigned short* __restrict__ dst){
    int idx = blockIdx.x*256 + threadIdx.x;
    if (idx >= 4096) return;
    dst[idx] = f2bf(src[idx]);
}

// M_i = W1_i + W2_i @ W1_i, output bf16 [i][co][ci]
__global__ void k_fuse_res(const float* __restrict__ w1, const float* __restrict__ w2,
                           unsigned short* __restrict__ mt){
    int idx = blockIdx.x*256 + threadIdx.x;
    if (idx >= 5*4096) return;
    int i = idx >> 12; int r = idx & 4095;
    int co = r >> 6; int ci = r & 63;
    const float* W1 = w1 + i*4096;
    const float* W2 = w2 + i*4096;
    float m = W1[co*64+ci];
    for (int k=0;k<64;++k) m += W2[co*64+k]*W1[k*64+ci];
    mt[idx] = f2bf(m);
}

// dst[ci*64+co] = src[co*64+ci]  (fp32, for pool 1x1 convs)
__global__ void k_transpose1(const float* __restrict__ src, float* __restrict__ dst){
    int idx = blockIdx.x*256 + threadIdx.x;
    if (idx >= 4096) return;
    int ci = idx >> 6; int co = idx & 63;
    dst[idx] = src[co*64+ci];
}

// ============ fvl [64][VOL] fp32 -> [VOL][64] bf16 (LDS transpose) ============
__global__ __launch_bounds__(256) void k_tobf16v(const float* __restrict__ src,
                                                 unsigned short* __restrict__ dst){
    __shared__ unsigned short lds[64*66];
    int tid = threadIdx.x;
    long vbase = (long)blockIdx.x*64;
    int v = tid & 63;
    int cg = tid >> 6;
#pragma unroll
    for (int k=0;k<16;++k){
        int ci = cg*16 + k;
        lds[v*66 + ci] = f2bf(src[(long)ci*VOL + vbase + v]);
    }
    __syncthreads();
#pragma unroll
    for (int it=0; it<2; ++it){
        int chunk = it*256 + tid;       // 512 chunks = 64v x 8 groups
        int vv = chunk >> 3, gp = chunk & 7;
        const unsigned short* s = lds + vv*66 + gp*8;
        unsigned int w0 = (unsigned)s[0] | ((unsigned)s[1]<<16);
        unsigned int w1 = (unsigned)s[2] | ((unsigned)s[3]<<16);
        unsigned int w2 = (unsigned)s[4] | ((unsigned)s[5]<<16);
        unsigned int w3 = (unsigned)s[6] | ((unsigned)s[7]<<16);
        u32x4v q = {w0,w1,w2,w3};
        *(u32x4v*)(dst + (vbase+vv)*64 + gp*8) = q;
    }
}

// ============ MFMA conv3x3x3, BRANCH-FREE K-loop ============
// in/out [VOL][64] bf16, wt [27][co][ci] bf16
// wave: 64co x 64vox; block: 4 waves = 256 voxels (2 W-rows)
// Out-of-bounds taps: address clamped to a safe in-range voxel (unconditional
// load), value zeroed by cndmask -> no exec-mask branches, straight-line 54-step
// K-loop the scheduler can pipeline.
template<bool AUX, bool RELU>
__global__ __launch_bounds__(256,3) void k_conv3m(
    const unsigned short* __restrict__ in, const unsigned short* __restrict__ wt,
    const unsigned short* __restrict__ aux, const unsigned short* __restrict__ auxw,
    unsigned short* __restrict__ out)
{
    const int lane = threadIdx.x & 63;
    const int wave = threadIdx.x >> 6;
    const int ll = lane & 15;
    const int kg = lane >> 4;
    const int vb = blockIdx.x*256 + wave*64;
    const int h = (vb >> 7) & 63;
    const int d = vb >> 13;

    f32x4 acc[4][4];
#pragma unroll
    for (int a=0;a<4;++a)
#pragma unroll
        for (int b=0;b<4;++b) acc[a][b] = (f32x4){0.f,0.f,0.f,0.f};
    const bf16x8 zero = {0,0,0,0,0,0,0,0};

#pragma unroll
    for (int kd=0; kd<3; ++kd){
        const int dd = d + kd - 1;
        const bool okd = (unsigned)dd < 48u;
#pragma unroll
        for (int kh=0; kh<3; ++kh){
            const int hh = h + kh - 1;
            const bool okdh = okd && ((unsigned)hh < 64u);
#pragma unroll
            for (int kw=0; kw<3; ++kw){
                const int tap = (kd*3+kh)*3+kw;
                const long dv = (long)((kd-1)*8192 + (kh-1)*128 + (kw-1));
                const unsigned short* wk = wt + tap*4096;
#pragma unroll
                for (int khalf=0; khalf<2; ++khalf){
                    const int ko = khalf*32 + kg*8;
                    bf16x8 afr[4];
#pragma unroll
                    for (int t=0;t<4;++t)
                        afr[t] = *(const bf16x8*)(wk + (t*16+ll)*64 + ko);
#pragma unroll
                    for (int vt=0; vt<4; ++vt){
                        const int vx = vb + vt*16 + ll;
                        const bool ok = okdh && ((unsigned)((vx & 127) + kw - 1) < 128u);
                        const long va = ok ? ((long)vx + dv) : (long)vx;   // always in-bounds
                        bf16x8 bfr = *(const bf16x8*)(in + va*64 + ko);
                        bfr = ok ? bfr : zero;                              // cndmask, no branch
#pragma unroll
                        for (int t=0;t<4;++t)
                            acc[t][vt] = __builtin_amdgcn_mfma_f32_16x16x32_bf16(afr[t], bfr, acc[t][vt], 0,0,0);
                    }
                }
            }
        }
    }
    if (AUX){
#pragma unroll
        for (int khalf=0; khalf<2; ++khalf){
            const int ko = khalf*32 + kg*8;
            bf16x8 afr[4];
#pragma unroll
            for (int t=0;t<4;++t)
                afr[t] = *(const bf16x8*)(auxw + (t*16+ll)*64 + ko);
#pragma unroll
            for (int vt=0; vt<4; ++vt){
                int vx = vb + vt*16 + ll;
                bf16x8 bfr = *(const bf16x8*)(aux + (long)vx*64 + ko);
#pragma unroll
                for (int t=0;t<4;++t)
                    acc[t][vt] = __builtin_amdgcn_mfma_f32_16x16x32_bf16(afr[t], bfr, acc[t][vt], 0,0,0);
            }
        }
    }
#pragma unroll
    for (int vt=0; vt<4; ++vt){
        int vx = vb + vt*16 + ll;
        unsigned short* op = out + (long)vx*64 + kg*4;
#pragma unroll
        for (int t=0;t<4;++t){
            float r0 = acc[t][vt][0], r1 = acc[t][vt][1], r2 = acc[t][vt][2], r3 = acc[t][vt][3];
            if (RELU){ r0=fmaxf(r0,0.f); r1=fmaxf(r1,0.f); r2=fmaxf(r2,0.f); r3=fmaxf(r3,0.f); }
            unsigned int lo = (unsigned)f2bf(r0) | ((unsigned)f2bf(r1)<<16);
            unsigned int hi = (unsigned)f2bf(r2) | ((unsigned)f2bf(r3)<<16);
            u32x2v q = {lo, hi};
            *(u32x2v*)(op + t*16) = q;
        }
    }
}

// ============ MFMA 1x1 conv (fused residual), relu; wt [co][ci] bf16 ============
__global__ __launch_bounds__(256) void k_conv1m(const unsigned short* __restrict__ in,
        const unsigned short* __restrict__ wt, unsigned short* __restrict__ out){
    const int lane = threadIdx.x & 63;
    const int wave = threadIdx.x >> 6;
    const int ll = lane & 15;
    const int kg = lane >> 4;
    const int vb = blockIdx.x*256 + wave*64;

    f32x4 acc[4][4];
#pragma unroll
    for (int a=0;a<4;++a)
#pragma unroll
        for (int b=0;b<4;++b) acc[a][b] = (f32x4){0.f,0.f,0.f,0.f};

#pragma unroll
    for (int khalf=0; khalf<2; ++khalf){
        const int ko = khalf*32 + kg*8;
        bf16x8 afr[4];
#pragma unroll
        for (int t=0;t<4;++t)
            afr[t] = *(const bf16x8*)(wt + (t*16+ll)*64 + ko);
#pragma unroll
        for (int vt=0; vt<4; ++vt){
            bf16x8 bfr = *(const bf16x8*)(in + (long)(vb+vt*16+ll)*64 + ko);
#pragma unroll
            for (int t=0;t<4;++t)
                acc[t][vt] = __builtin_amdgcn_mfma_f32_16x16x32_bf16(afr[t], bfr, acc[t][vt], 0,0,0);
        }
    }
#pragma unroll
    for (int vt=0; vt<4; ++vt){
        int vx = vb + vt*16 + ll;
        unsigned short* op = out + (long)vx*64 + kg*4;
#pragma unroll
        for (int t=0;t<4;++t){
            float r0 = fmaxf(acc[t][vt][0],0.f), r1 = fmaxf(acc[t][vt][1],0.f);
            float r2 = fmaxf(acc[t][vt][2],0.f), r3 = fmaxf(acc[t][vt][3],0.f);
            unsigned int lo = (unsigned)f2bf(r0) | ((unsigned)f2bf(r1)<<16);
            unsigned int hi = (unsigned)f2bf(r2) | ((unsigned)f2bf(r3)<<16);
            u32x2v q = {lo, hi};
            *(u32x2v*)(op + t*16) = q;
        }
    }
}

// ============ global pool partials: 384 blocks x 1024 vox, part[b][64] ============
__global__ __launch_bounds__(256) void k_gpool(const unsigned short* __restrict__ in,
                                               float* __restrict__ part){
    __shared__ float sm[32][64];
    int cg = threadIdx.x & 7;
    int r  = threadIdx.x >> 3;
    long vb = (long)blockIdx.x*1024;
    float a[8];
#pragma unroll
    for (int j=0;j<8;++j) a[j]=0.f;
    for (int v = r; v < 1024; v += 32){
        u32x4v q = *(const u32x4v*)(in + (vb+v)*64 + cg*8);
#pragma unroll
        for (int e=0;e<4;++e){
            a[e*2]   += bflo(q[e]);
            a[e*2+1] += bfhi(q[e]);
        }
    }
#pragma unroll
    for (int j=0;j<8;++j) sm[r][cg*8+j] = a[j];
    __syncthreads();
    if (threadIdx.x < 64){
        float s=0.f;
        for (int rr=0;rr<32;++rr) s += sm[rr][threadIdx.x];
        part[blockIdx.x*64 + threadIdx.x] = s;
    }
}

// reduce partials -> g, then gc[co] = sum_ci wp0[co][ci] * g[ci] / VOL
__global__ void k_gfin(const float* __restrict__ part, const float* __restrict__ wp0,
                       float* __restrict__ gc){
    __shared__ float sg[64];
    int t = threadIdx.x;
    if (t < 64){
        float s=0.f;
        for (int b=0;b<384;++b) s += part[b*64 + t];
        sg[t] = s * (1.0f/(float)VOL);
    }
    __syncthreads();
    if (t < 64){
        float s=0.f;
        for (int ci=0;ci<64;++ci) s += wp0[t*64+ci]*sg[ci];
        gc[t] = s;
    }
}

// ============ avg pool (VALID, stride=ksize), bf16 vox-major in, fp32 [c][cells] out ============
__global__ void k_avgpool(const unsigned short* __restrict__ in, float* __restrict__ out,
                          int od,int oh,int ow,int kd,int kh,int kw){
    int ovol = od*oh*ow;
    int idx = blockIdx.x*256 + threadIdx.x;
    if (idx >= 64*ovol) return;
    int c = idx & 63; int cell = idx >> 6;
    int z = cell/(oh*ow); int rem = cell - z*(oh*ow); int y = rem/ow; int x = rem - y*ow;
    float s = 0.f;
    for (int a=0;a<kd;++a)
        for (int b=0;b<kh;++b)
            for (int e=0;e<kw;++e){
                long v = ((long)(z*kd+a)*64 + (y*kh+b))*128 + (x*kw+e);
                s += bf2f(in[v*64 + c]);
            }
    out[c*ovol + cell] = s / (float)(kd*kh*kw);
}

// ============ 1x1 conv fp32 on pooled grids; wt [ci][co], OUT voxel-major [cell][64] ============
__global__ void k_conv1(const float* __restrict__ in, const float* __restrict__ wt,
                        float* __restrict__ out, int vol){
    int v = blockIdx.x*256 + threadIdx.x;
    if (v >= vol) return;
    float acc[64];
#pragma unroll
    for (int i=0;i<64;++i) acc[i]=0.f;
    for (int ci=0; ci<64; ++ci){
        float xv = in[ci*vol + v];
        const float* wr = wt + ci*64;
#pragma unroll
        for (int co=0; co<64; ++co) acc[co] = fmaf(wr[co], xv, acc[co]);
    }
    float* op = out + (long)v*64;
#pragma unroll
    for (int q=0;q<16;++q){
        f32x4 t = {acc[q*4], acc[q*4+1], acc[q*4+2], acc[q*4+3]};
        *(f32x4*)(op + q*4) = t;
    }
}

// ============ trilinear gather ============
__device__ __forceinline__ void tri_setup(int d,int h,int w,int gd,int gh,int gw,
                                          int* o, float* wt){
    float fz = (d+0.5f)*((float)gd/(float)DD) - 0.5f;
    float fy = (h+0.5f)*((float)gh/(float)HH) - 0.5f;
    float fx = (w+0.5f)*((float)gw/(float)WW) - 0.5f;
    float z0f = floorf(fz), y0f = floorf(fy), x0f = floorf(fx);
    float tz = fz - z0f, ty = fy - y0f, tx = fx - x0f;
    int z0 = (int)z0f, y0 = (int)y0f, x0 = (int)x0f;
    int z1 = z0+1, y1 = y0+1, x1 = x0+1;
    z0 = min(max(z0,0),gd-1); z1 = min(max(z1,0),gd-1);
    y0 = min(max(y0,0),gh-1); y1 = min(max(y1,0),gh-1);
    x0 = min(max(x0,0),gw-1); x1 = min(max(x1,0),gw-1);
    o[0] = (z0*gh+y0)*gw+x0; wt[0] = (1-tz)*(1-ty)*(1-tx);
    o[1] = (z0*gh+y0)*gw+x1; wt[1] = (1-tz)*(1-ty)*tx;
    o[2] = (z0*gh+y1)*gw+x0; wt[2] = (1-tz)*ty*(1-tx);
    o[3] = (z0*gh+y1)*gw+x1; wt[3] = (1-tz)*ty*tx;
    o[4] = (z1*gh+y0)*gw+x0; wt[4] = tz*(1-ty)*(1-tx);
    o[5] = (z1*gh+y0)*gw+x1; wt[5] = tz*(1-ty)*tx;
    o[6] = (z1*gh+y1)*gw+x0; wt[6] = tz*ty*(1-tx);
    o[7] = (z1*gh+y1)*gw+x1; wt[7] = tz*ty*tx;
}

// out = relu((xc + 0.25*(gc + up(p2)+up(p3)+up(p4)))/2)
// pools are voxel-major [cell][64] -> vectorized f32x4 gathers, no LDS.
// writes xout fp32 [64][VOL] and xv bf16 [VOL][64]
__global__ __launch_bounds__(256) void k_combine(
        const unsigned short* __restrict__ xc, const float* __restrict__ gc,
        const float* __restrict__ p2, const float* __restrict__ p3,
        const float* __restrict__ p4, float* __restrict__ xout,
        unsigned short* __restrict__ xv){
    int tid = threadIdx.x;
    long v = (long)blockIdx.x*256 + tid;
    int w = v & 127; int h = (v>>7)&63; int d = v>>13;
    int o2[8], o3[8], o4[8];
    float w2_[8], w3_[8], w4_[8];
    tri_setup(d,h,w, 8,8,8,    o2, w2_);
    tri_setup(d,h,w, 16,16,16, o3, w3_);
    tri_setup(d,h,w, 24,32,25, o4, w4_);
#pragma unroll
    for (int half=0; half<2; ++half){
        float res[32];
#pragma unroll
        for (int j=0;j<32;++j) res[j] = gc[half*32+j];
#pragma unroll
        for (int t=0;t<8;++t){
            const float* b2 = p2 + (long)o2[t]*64 + half*32;
#pragma unroll
            for (int q=0;q<8;++q){
                f32x4 x4 = *(const f32x4*)(b2 + q*4);
                res[q*4+0] = fmaf(w2_[t], x4[0], res[q*4+0]);
                res[q*4+1] = fmaf(w2_[t], x4[1], res[q*4+1]);
                res[q*4+2] = fmaf(w2_[t], x4[2], res[q*4+2]);
                res[q*4+3] = fmaf(w2_[t], x4[3], res[q*4+3]);
            }
        }
#pragma unroll
        for (int t=0;t<8;++t){
            const float* b3 = p3 + (long)o3[t]*64 + half*32;
#pragma unroll
            for (int q=0;q<8;++q){
                f32x4 x4 = *(const f32x4*)(b3 + q*4);
                res[q*4+0] = fmaf(w3_[t], x4[0], res[q*4+0]);
                res[q*4+1] = fmaf(w3_[t], x4[1], res[q*4+1]);
                res[q*4+2] = fmaf(w3_[t], x4[2], res[q*4+2]);
                res[q*4+3] = fmaf(w3_[t], x4[3], res[q*4+3]);
            }
        }
#pragma unroll
        for (int t=0;t<8;++t){
            const float* b4 = p4 + (long)o4[t]*64 + half*32;
#pragma unroll
            for (int q=0;q<8;++q){
                f32x4 x4 = *(const f32x4*)(b4 + q*4);
                res[q*4+0] = fmaf(w4_[t], x4[0], res[q*4+0]);
                res[q*4+1] = fmaf(w4_[t], x4[1], res[q*4+1]);
                res[q*4+2] = fmaf(w4_[t], x4[2], res[q*4+2]);
                res[q*4+3] = fmaf(w4_[t], x4[3], res[q*4+3]);
            }
        }
        const u32x4v* xq = (const u32x4v*)(xc + v*64 + half*32);
#pragma unroll
        for (int q=0;q<4;++q){
            u32x4v qv = xq[q];
            unsigned int pk[4];
#pragma unroll
            for (int e=0;e<4;++e){
                int j = q*8 + e*2;
                float r0 = fmaxf((bflo(qv[e]) + 0.25f*res[j])*0.5f, 0.f);
                float r1 = fmaxf((bfhi(qv[e]) + 0.25f*res[j+1])*0.5f, 0.f);
                xout[(long)(half*32+j)*VOL + v]   = r0;
                xout[(long)(half*32+j+1)*VOL + v] = r1;
                pk[e] = (unsigned)f2bf(r0) | ((unsigned)f2bf(r1)<<16);
            }
            u32x4v pq = {pk[0],pk[1],pk[2],pk[3]};
            *(u32x4v*)(xv + v*64 + half*32 + q*8) = pq;
        }
    }
}

// ============ head conv3 64->1 + bias, branch-free fp32 ============
__global__ __launch_bounds__(256) void k_head(const unsigned short* __restrict__ in,
        const float* __restrict__ wr, const float* __restrict__ bias,
        float* __restrict__ out){
    int v = blockIdx.x*256 + threadIdx.x;
    int ww = v & 127; int h = (v>>7)&63; int d = v>>13;
    float s = bias[0];
#pragma unroll
    for (int kd=0;kd<3;++kd){
#pragma unroll
      for (int kh=0;kh<3;++kh){
#pragma unroll
        for (int kw=0;kw<3;++kw){
          const int tap=(kd*3+kh)*3+kw;
          const long dv = (long)((kd-1)*8192 + (kh-1)*128 + (kw-1));
          bool ok = ((unsigned)(d+kd-1)<48u) && ((unsigned)(h+kh-1)<64u) && ((unsigned)(ww+kw-1)<128u);
          long va = ok ? ((long)v + dv) : (long)v;
          const u32x4v* q4 = (const u32x4v*)(in + va*64);
          float ps = 0.f;
#pragma unroll
          for (int g=0; g<8; ++g){
              u32x4v q = q4[g];
#pragma unroll
              for (int e=0;e<4;++e){
                  int ci = g*8 + e*2;
                  ps += bflo(q[e])*wr[ci*27+tap] + bfhi(q[e])*wr[(ci+1)*27+tap];
              }
          }
          s += ok ? ps : 0.f;
        }
      }
    }
    out[v] = s;
}

// ================= workspace layout (bytes) =================
constexpr long OFF_V0  = 0;                       // bf16 vol: 50,331,648
constexpr long OFF_V1  = 50331648;                // bf16 vol
constexpr long OFF_WA1 = 100663296;               // 221,184
constexpr long OFF_WA2 = OFF_WA1 + 221184;
constexpr long OFF_WC1 = OFF_WA2 + 221184;
constexpr long OFF_NIN = OFF_WC1 + 221184;        // 8,192
constexpr long OFF_MT  = OFF_NIN + 8192;          // 40,960
constexpr long OFF_WPT = OFF_MT + 40960;          // 49,152 (wp1..wp3 fp32 transposed)
constexpr long OFF_GP  = OFF_WPT + 49152;         // 98,304 (384x64 partials)
constexpr long OFF_GC  = OFF_GP + 98304;          // 256
constexpr long OFF_P2  = OFF_GC + 256;            // 131,072
constexpr long OFF_P2C = OFF_P2 + 131072;
constexpr long OFF_P3  = OFF_P2C + 131072;        // 1,048,576
constexpr long OFF_P3C = OFF_P3 + 1048576;
constexpr long OFF_P4  = OFF_P3C + 1048576;       // 4,915,200
constexpr long OFF_P4C = OFF_P4 + 4915200;
// end = 113,713,408 bytes

extern "C" void kernel_launch(void* const* d_in, const int* in_sizes, int n_in,
                              void* d_out, int out_size, void* d_ws, size_t ws_size,
                              hipStream_t stream) {
    const float* fvl  = (const float*)d_in[0];
    const float* w_a1 = (const float*)d_in[1];
    const float* w_a2 = (const float*)d_in[2];
    const float* wnin = (const float*)d_in[3];
    const float* w1s  = (const float*)d_in[4];
    const float* w2s  = (const float*)d_in[5];
    const float* wp0  = (const float*)d_in[6];
    const float* wp1  = (const float*)d_in[7];
    const float* wp2  = (const float*)d_in[8];
    const float* wp3  = (const float*)d_in[9];
    const float* wc1  = (const float*)d_in[10];
    const float* wc2  = (const float*)d_in[11];
    const float* bc   = (const float*)d_in[12];

    char* ws = (char*)d_ws;
    unsigned short* V0   = (unsigned short*)(ws + OFF_V0);
    unsigned short* V1   = (unsigned short*)(ws + OFF_V1);
    unsigned short* wa1t = (unsigned short*)(ws + OFF_WA1);
    unsigned short* wa2t = (unsigned short*)(ws + OFF_WA2);
    unsigned short* wc1t = (unsigned short*)(ws + OFF_WC1);
    unsigned short* nint = (unsigned short*)(ws + OFF_NIN);
    unsigned short* Mt   = (unsigned short*)(ws + OFF_MT);
    float* wpt  = (float*)(ws + OFF_WPT);
    float* gp   = (float*)(ws + OFF_GP);
    float* gc   = (float*)(ws + OFF_GC);
    float* p2   = (float*)(ws + OFF_P2);
    float* p2c  = (float*)(ws + OFF_P2C);
    float* p3   = (float*)(ws + OFF_P3);
    float* p3c  = (float*)(ws + OFF_P3C);
    float* p4   = (float*)(ws + OFF_P4);
    float* p4c  = (float*)(ws + OFF_P4C);

    float* Xout = (float*)d_out;                       // [64][VOL] fp32
    float* Cout = Xout + (long)NC*VOL;                 // [VOL] fp32
    unsigned short* V2 = (unsigned short*)d_out;       // transient bf16 vol inside x region

    const int GB = VOL/256;    // 1536 blocks for MFMA volume kernels

    // --- prep ---
    k_wprep3<<<(27*64*64+255)/256,256,0,stream>>>(w_a1, wa1t);
    k_wprep3<<<(27*64*64+255)/256,256,0,stream>>>(w_a2, wa2t);
    k_wprep3<<<(27*64*64+255)/256,256,0,stream>>>(wc1, wc1t);
    k_wprep1<<<16,256,0,stream>>>(wnin, nint);
    k_fuse_res<<<80,256,0,stream>>>(w1s, w2s, Mt);
    k_transpose1<<<16,256,0,stream>>>(wp1, wpt + 0*4096);
    k_transpose1<<<16,256,0,stream>>>(wp2, wpt + 1*4096);
    k_transpose1<<<16,256,0,stream>>>(wp3, wpt + 2*4096);
    k_tobf16v<<<VOL/64,256,0,stream>>>(fvl, V0);

    // --- stage A: V1 = conv3(V0, wa1) ---
    k_conv3m<false,false><<<GB,256,0,stream>>>(V0, wa1t, nullptr, nullptr, V1);
    // --- stage B: V2 = conv3(V1, wa2) + conv1(V0, nin) ---
    k_conv3m<true,false><<<GB,256,0,stream>>>(V1, wa2t, V0, nint, V2);

    // --- stage C: 5x fused residual 1x1 (relu), ping-pong V2 <-> V1, ends in V1 ---
    unsigned short* cur = V2; unsigned short* nxt = V1;
    for (int i=0;i<5;++i){
        k_conv1m<<<GB,256,0,stream>>>(cur, Mt + i*4096, nxt);
        unsigned short* t = cur; cur = nxt; nxt = t;
    }
    // cur == V1

    // --- stage D: pool pyramid ---
    k_gpool<<<384,256,0,stream>>>(cur, gp);
    k_gfin<<<1,64,0,stream>>>(gp, wp0, gc);

    k_avgpool<<<(64*512+255)/256,256,0,stream>>>(cur, p2, 8,8,8,   6,8,16);
    k_conv1<<<2,256,0,stream>>>(p2, wpt + 0*4096, p2c, 512);

    k_avgpool<<<(64*4096+255)/256,256,0,stream>>>(cur, p3, 16,16,16, 3,4,8);
    k_conv1<<<16,256,0,stream>>>(p3, wpt + 1*4096, p3c, 4096);

    k_avgpool<<<(64*19200+255)/256,256,0,stream>>>(cur, p4, 24,32,25, 2,2,5);
    k_conv1<<<75,256,0,stream>>>(p4, wpt + 2*4096, p4c, 19200);

    // --- combine: write x (fp32, d_out) + bf16 copy into V0 region ---
    k_combine<<<GB,256,0,stream>>>(cur, gc, p2c, p3c, p4c, Xout, V0);

    // --- head: V1 = relu(conv3(x, wc1)); Cout = conv3(V1, wc2) + bc ---
    k_conv3m<false,true><<<GB,256,0,stream>>>(V0, wc1t, nullptr, nullptr, V1);
    k_head<<<GB,256,0,stream>>>(V1, wc2, bc, Cout);
}

// Round 5
// 1592.731 us; speedup vs baseline: 1.2936x; 1.2936x over previous
//
#include <hip/hip_runtime.h>
#include <math.h>

#define DD 48
#define HH 64
#define WW 128
#define VOL (DD*HH*WW)   // 393216
#define NC 64

typedef __attribute__((ext_vector_type(8))) short bf16x8;
typedef __attribute__((ext_vector_type(4))) float f32x4;
typedef __attribute__((ext_vector_type(4))) unsigned int u32x4v;
typedef __attribute__((ext_vector_type(2))) unsigned int u32x2v;

__device__ __forceinline__ float bflo(unsigned int u){
    union { unsigned int i; float f; } x; x.i = u<<16; return x.f; }
__device__ __forceinline__ float bfhi(unsigned int u){
    union { unsigned int i; float f; } x; x.i = u & 0xffff0000u; return x.f; }
__device__ __forceinline__ float bf2f(unsigned short u){
    union { unsigned int i; float f; } x; x.i = ((unsigned int)u)<<16; return x.f; }
__device__ __forceinline__ unsigned short f2bf(float f){
    union { float f; unsigned int i; } x; x.f = f;
    unsigned int i = x.i;
    return (unsigned short)((i + 0x7fffu + ((i>>16)&1u)) >> 16);  // RNE
}

// ================= weight prep =================

// src [co=64][ci=64][k=27] fp32 -> dst [k=27][co=64][ci=64] bf16
__global__ void k_wprep3(const float* __restrict__ src, unsigned short* __restrict__ dst){
    int idx = blockIdx.x*256 + threadIdx.x;
    if (idx >= 27*64*64) return;
    int ci = idx & 63; int t = idx >> 6; int co = t & 63; int k = t >> 6;
    dst[idx] = f2bf(src[(co*64+ci)*27 + k]);
}

// src [co][ci] fp32 -> dst [co][ci] bf16 (elementwise convert)
__global__ void k_wprep1(const float* __restrict__ src, unsigned short* __restrict__ dst){
    int idx = blockIdx.x*256 + threadIdx.x;
    if (idx >= 4096) return;
    dst[idx] = f2bf(src[idx]);
}

// wc2 [co=64][tap=27] fp32 -> dst [taprow=32][co=64] bf16 (taps >=27 zero)
__global__ void k_wprep2(const float* __restrict__ src, unsigned short* __restrict__ dst){
    int idx = blockIdx.x*256 + threadIdx.x;
    if (idx >= 32*64) return;
    int co = idx & 63; int row = idx >> 6;
    float v = (row < 27) ? src[co*27 + row] : 0.f;
    dst[row*64 + co] = f2bf(v);
}

// M_i = W1_i + W2_i @ W1_i, output bf16 [i][co][ci]
__global__ void k_fuse_res(const float* __restrict__ w1, const float* __restrict__ w2,
                           unsigned short* __restrict__ mt){
    int idx = blockIdx.x*256 + threadIdx.x;
    if (idx >= 5*4096) return;
    int i = idx >> 12; int r = idx & 4095;
    int co = r >> 6; int ci = r & 63;
    const float* W1 = w1 + i*4096;
    const float* W2 = w2 + i*4096;
    float m = W1[co*64+ci];
    for (int k=0;k<64;++k) m += W2[co*64+k]*W1[k*64+ci];
    mt[idx] = f2bf(m);
}

// dst[ci*64+co] = src[co*64+ci]  (fp32, for pool 1x1 convs)
__global__ void k_transpose1(const float* __restrict__ src, float* __restrict__ dst){
    int idx = blockIdx.x*256 + threadIdx.x;
    if (idx >= 4096) return;
    int ci = idx >> 6; int co = idx & 63;
    dst[idx] = src[co*64+ci];
}

// ============ fvl [64][VOL] fp32 -> [VOL][64] bf16 (LDS transpose) ============
__global__ __launch_bounds__(256) void k_tobf16v(const float* __restrict__ src,
                                                 unsigned short* __restrict__ dst){
    __shared__ unsigned short lds[64*66];
    int tid = threadIdx.x;
    long vbase = (long)blockIdx.x*64;
    int v = tid & 63;
    int cg = tid >> 6;
#pragma unroll
    for (int k=0;k<16;++k){
        int ci = cg*16 + k;
        lds[v*66 + ci] = f2bf(src[(long)ci*VOL + vbase + v]);
    }
    __syncthreads();
#pragma unroll
    for (int it=0; it<2; ++it){
        int chunk = it*256 + tid;       // 512 chunks = 64v x 8 groups
        int vv = chunk >> 3, gp = chunk & 7;
        const unsigned short* s = lds + vv*66 + gp*8;
        unsigned int w0 = (unsigned)s[0] | ((unsigned)s[1]<<16);
        unsigned int w1 = (unsigned)s[2] | ((unsigned)s[3]<<16);
        unsigned int w2 = (unsigned)s[4] | ((unsigned)s[5]<<16);
        unsigned int w3 = (unsigned)s[6] | ((unsigned)s[7]<<16);
        u32x4v q = {w0,w1,w2,w3};
        *(u32x4v*)(dst + (vbase+vv)*64 + gp*8) = q;
    }
}

// ============ MFMA conv3x3x3, BRANCH-FREE K-loop ============
// in/out [VOL][64] bf16, wt [27][co][ci] bf16
// wave: 64co x 64vox; block: 4 waves = 256 voxels (2 W-rows)
template<bool AUX, bool RELU>
__global__ __launch_bounds__(256,3) void k_conv3m(
    const unsigned short* __restrict__ in, const unsigned short* __restrict__ wt,
    const unsigned short* __restrict__ aux, const unsigned short* __restrict__ auxw,
    unsigned short* __restrict__ out)
{
    const int lane = threadIdx.x & 63;
    const int wave = threadIdx.x >> 6;
    const int ll = lane & 15;
    const int kg = lane >> 4;
    const int vb = blockIdx.x*256 + wave*64;
    const int h = (vb >> 7) & 63;
    const int d = vb >> 13;

    f32x4 acc[4][4];
#pragma unroll
    for (int a=0;a<4;++a)
#pragma unroll
        for (int b=0;b<4;++b) acc[a][b] = (f32x4){0.f,0.f,0.f,0.f};
    const bf16x8 zero = {0,0,0,0,0,0,0,0};

#pragma unroll
    for (int kd=0; kd<3; ++kd){
        const int dd = d + kd - 1;
        const bool okd = (unsigned)dd < 48u;
#pragma unroll
        for (int kh=0; kh<3; ++kh){
            const int hh = h + kh - 1;
            const bool okdh = okd && ((unsigned)hh < 64u);
#pragma unroll
            for (int kw=0; kw<3; ++kw){
                const int tap = (kd*3+kh)*3+kw;
                const long dv = (long)((kd-1)*8192 + (kh-1)*128 + (kw-1));
                const unsigned short* wk = wt + tap*4096;
#pragma unroll
                for (int khalf=0; khalf<2; ++khalf){
                    const int ko = khalf*32 + kg*8;
                    bf16x8 afr[4];
#pragma unroll
                    for (int t=0;t<4;++t)
                        afr[t] = *(const bf16x8*)(wk + (t*16+ll)*64 + ko);
#pragma unroll
                    for (int vt=0; vt<4; ++vt){
                        const int vx = vb + vt*16 + ll;
                        const bool ok = okdh && ((unsigned)((vx & 127) + kw - 1) < 128u);
                        const long va = ok ? ((long)vx + dv) : (long)vx;   // always in-bounds
                        bf16x8 bfr = *(const bf16x8*)(in + va*64 + ko);
                        bfr = ok ? bfr : zero;                              // cndmask, no branch
#pragma unroll
                        for (int t=0;t<4;++t)
                            acc[t][vt] = __builtin_amdgcn_mfma_f32_16x16x32_bf16(afr[t], bfr, acc[t][vt], 0,0,0);
                    }
                }
            }
        }
    }
    if (AUX){
#pragma unroll
        for (int khalf=0; khalf<2; ++khalf){
            const int ko = khalf*32 + kg*8;
            bf16x8 afr[4];
#pragma unroll
            for (int t=0;t<4;++t)
                afr[t] = *(const bf16x8*)(auxw + (t*16+ll)*64 + ko);
#pragma unroll
            for (int vt=0; vt<4; ++vt){
                int vx = vb + vt*16 + ll;
                bf16x8 bfr = *(const bf16x8*)(aux + (long)vx*64 + ko);
#pragma unroll
                for (int t=0;t<4;++t)
                    acc[t][vt] = __builtin_amdgcn_mfma_f32_16x16x32_bf16(afr[t], bfr, acc[t][vt], 0,0,0);
            }
        }
    }
#pragma unroll
    for (int vt=0; vt<4; ++vt){
        int vx = vb + vt*16 + ll;
        unsigned short* op = out + (long)vx*64 + kg*4;
#pragma unroll
        for (int t=0;t<4;++t){
            float r0 = acc[t][vt][0], r1 = acc[t][vt][1], r2 = acc[t][vt][2], r3 = acc[t][vt][3];
            if (RELU){ r0=fmaxf(r0,0.f); r1=fmaxf(r1,0.f); r2=fmaxf(r2,0.f); r3=fmaxf(r3,0.f); }
            unsigned int lo = (unsigned)f2bf(r0) | ((unsigned)f2bf(r1)<<16);
            unsigned int hi = (unsigned)f2bf(r2) | ((unsigned)f2bf(r3)<<16);
            u32x2v q = {lo, hi};
            *(u32x2v*)(op + t*16) = q;
        }
    }
}

// ============ MFMA 1x1 conv (fused residual), relu; wt [co][ci] bf16 ============
__global__ __launch_bounds__(256) void k_conv1m(const unsigned short* __restrict__ in,
        const unsigned short* __restrict__ wt, unsigned short* __restrict__ out){
    const int lane = threadIdx.x & 63;
    const int wave = threadIdx.x >> 6;
    const int ll = lane & 15;
    const int kg = lane >> 4;
    const int vb = blockIdx.x*256 + wave*64;

    f32x4 acc[4][4];
#pragma unroll
    for (int a=0;a<4;++a)
#pragma unroll
        for (int b=0;b<4;++b) acc[a][b] = (f32x4){0.f,0.f,0.f,0.f};

#pragma unroll
    for (int khalf=0; khalf<2; ++khalf){
        const int ko = khalf*32 + kg*8;
        bf16x8 afr[4];
#pragma unroll
        for (int t=0;t<4;++t)
            afr[t] = *(const bf16x8*)(wt + (t*16+ll)*64 + ko);
#pragma unroll
        for (int vt=0; vt<4; ++vt){
            bf16x8 bfr = *(const bf16x8*)(in + (long)(vb+vt*16+ll)*64 + ko);
#pragma unroll
            for (int t=0;t<4;++t)
                acc[t][vt] = __builtin_amdgcn_mfma_f32_16x16x32_bf16(afr[t], bfr, acc[t][vt], 0,0,0);
        }
    }
#pragma unroll
    for (int vt=0; vt<4; ++vt){
        int vx = vb + vt*16 + ll;
        unsigned short* op = out + (long)vx*64 + kg*4;
#pragma unroll
        for (int t=0;t<4;++t){
            float r0 = fmaxf(acc[t][vt][0],0.f), r1 = fmaxf(acc[t][vt][1],0.f);
            float r2 = fmaxf(acc[t][vt][2],0.f), r3 = fmaxf(acc[t][vt][3],0.f);
            unsigned int lo = (unsigned)f2bf(r0) | ((unsigned)f2bf(r1)<<16);
            unsigned int hi = (unsigned)f2bf(r2) | ((unsigned)f2bf(r3)<<16);
            u32x2v q = {lo, hi};
            *(u32x2v*)(op + t*16) = q;
        }
    }
}

// ============ head stage 1: t[tap][v] = sum_co V1[v][co]*wc2[co][tap]  (MFMA) ============
// wt2 [32 taprows][64 co] bf16; out t fp32 [27][VOL]
__global__ __launch_bounds__(256) void k_headt(const unsigned short* __restrict__ in,
        const unsigned short* __restrict__ wt2, float* __restrict__ t){
    const int lane = threadIdx.x & 63;
    const int wave = threadIdx.x >> 6;
    const int ll = lane & 15;
    const int kg = lane >> 4;
    const int vb = blockIdx.x*256 + wave*64;

    f32x4 acc[2][4];
#pragma unroll
    for (int a=0;a<2;++a)
#pragma unroll
        for (int b=0;b<4;++b) acc[a][b] = (f32x4){0.f,0.f,0.f,0.f};

#pragma unroll
    for (int khalf=0; khalf<2; ++khalf){
        const int ko = khalf*32 + kg*8;
        bf16x8 afr[2];
#pragma unroll
        for (int tl=0;tl<2;++tl)
            afr[tl] = *(const bf16x8*)(wt2 + (tl*16+ll)*64 + ko);
#pragma unroll
        for (int vt=0; vt<4; ++vt){
            bf16x8 bfr = *(const bf16x8*)(in + (long)(vb+vt*16+ll)*64 + ko);
#pragma unroll
            for (int tl=0;tl<2;++tl)
                acc[tl][vt] = __builtin_amdgcn_mfma_f32_16x16x32_bf16(afr[tl], bfr, acc[tl][vt], 0,0,0);
        }
    }
#pragma unroll
    for (int vt=0; vt<4; ++vt){
        int vx = vb + vt*16 + ll;
#pragma unroll
        for (int tl=0;tl<2;++tl){
#pragma unroll
            for (int r=0;r<4;++r){
                int tap = tl*16 + kg*4 + r;
                if (tap < 27) t[(long)tap*VOL + vx] = acc[tl][vt][r];
            }
        }
    }
}

// ============ head stage 2: out[v] = bias + sum_tap t[tap][v+dv(tap)] ============
__global__ __launch_bounds__(256) void k_heads(const float* __restrict__ t,
        const float* __restrict__ bias, float* __restrict__ out){
    int v = blockIdx.x*256 + threadIdx.x;
    int ww = v & 127; int h = (v>>7)&63; int d = v>>13;
    float s = bias[0];
#pragma unroll
    for (int kd=0;kd<3;++kd){
#pragma unroll
      for (int kh=0;kh<3;++kh){
#pragma unroll
        for (int kw=0;kw<3;++kw){
            const int tap = (kd*3+kh)*3+kw;
            const long dv = (long)((kd-1)*8192 + (kh-1)*128 + (kw-1));
            bool ok = ((unsigned)(d+kd-1)<48u) && ((unsigned)(h+kh-1)<64u) && ((unsigned)(ww+kw-1)<128u);
            long va = ok ? ((long)v + dv) : (long)v;
            float x = t[(long)tap*VOL + va];
            s += ok ? x : 0.f;
        }
      }
    }
    out[v] = s;
}

// ============ global pool partials: 384 blocks x 1024 vox, part[b][64] ============
__global__ __launch_bounds__(256) void k_gpool(const unsigned short* __restrict__ in,
                                               float* __restrict__ part){
    __shared__ float sm[32][64];
    int cg = threadIdx.x & 7;
    int r  = threadIdx.x >> 3;
    long vb = (long)blockIdx.x*1024;
    float a[8];
#pragma unroll
    for (int j=0;j<8;++j) a[j]=0.f;
    for (int v = r; v < 1024; v += 32){
        u32x4v q = *(const u32x4v*)(in + (vb+v)*64 + cg*8);
#pragma unroll
        for (int e=0;e<4;++e){
            a[e*2]   += bflo(q[e]);
            a[e*2+1] += bfhi(q[e]);
        }
    }
#pragma unroll
    for (int j=0;j<8;++j) sm[r][cg*8+j] = a[j];
    __syncthreads();
    if (threadIdx.x < 64){
        float s=0.f;
        for (int rr=0;rr<32;++rr) s += sm[rr][threadIdx.x];
        part[blockIdx.x*64 + threadIdx.x] = s;
    }
}

// reduce partials -> g, then gc[co] = sum_ci wp0[co][ci] * g[ci] / VOL
__global__ void k_gfin(const float* __restrict__ part, const float* __restrict__ wp0,
                       float* __restrict__ gc){
    __shared__ float sg[64];
    int t = threadIdx.x;
    if (t < 64){
        float s=0.f;
        for (int b=0;b<384;++b) s += part[b*64 + t];
        sg[t] = s * (1.0f/(float)VOL);
    }
    __syncthreads();
    if (t < 64){
        float s=0.f;
        for (int ci=0;ci<64;++ci) s += wp0[t*64+ci]*sg[ci];
        gc[t] = s;
    }
}

// ============ avg pool (VALID, stride=ksize), bf16 vox-major in, fp32 [c][cells] out ============
__global__ void k_avgpool(const unsigned short* __restrict__ in, float* __restrict__ out,
                          int od,int oh,int ow,int kd,int kh,int kw){
    int ovol = od*oh*ow;
    int idx = blockIdx.x*256 + threadIdx.x;
    if (idx >= 64*ovol) return;
    int c = idx & 63; int cell = idx >> 6;
    int z = cell/(oh*ow); int rem = cell - z*(oh*ow); int y = rem/ow; int x = rem - y*ow;
    float s = 0.f;
    for (int a=0;a<kd;++a)
        for (int b=0;b<kh;++b)
            for (int e=0;e<kw;++e){
                long v = ((long)(z*kd+a)*64 + (y*kh+b))*128 + (x*kw+e);
                s += bf2f(in[v*64 + c]);
            }
    out[c*ovol + cell] = s / (float)(kd*kh*kw);
}

// ============ 1x1 conv fp32 on pooled grids; wt [ci][co], OUT voxel-major [cell][64] ============
__global__ void k_conv1(const float* __restrict__ in, const float* __restrict__ wt,
                        float* __restrict__ out, int vol){
    int v = blockIdx.x*256 + threadIdx.x;
    if (v >= vol) return;
    float acc[64];
#pragma unroll
    for (int i=0;i<64;++i) acc[i]=0.f;
    for (int ci=0; ci<64; ++ci){
        float xv = in[ci*vol + v];
        const float* wr = wt + ci*64;
#pragma unroll
        for (int co=0; co<64; ++co) acc[co] = fmaf(wr[co], xv, acc[co]);
    }
    float* op = out + (long)v*64;
#pragma unroll
    for (int q=0;q<16;++q){
        f32x4 t = {acc[q*4], acc[q*4+1], acc[q*4+2], acc[q*4+3]};
        *(f32x4*)(op + q*4) = t;
    }
}

// ============ trilinear gather ============
__device__ __forceinline__ void tri_setup(int d,int h,int w,int gd,int gh,int gw,
                                          int* o, float* wt){
    float fz = (d+0.5f)*((float)gd/(float)DD) - 0.5f;
    float fy = (h+0.5f)*((float)gh/(float)HH) - 0.5f;
    float fx = (w+0.5f)*((float)gw/(float)WW) - 0.5f;
    float z0f = floorf(fz), y0f = floorf(fy), x0f = floorf(fx);
    float tz = fz - z0f, ty = fy - y0f, tx = fx - x0f;
    int z0 = (int)z0f, y0 = (int)y0f, x0 = (int)x0f;
    int z1 = z0+1, y1 = y0+1, x1 = x0+1;
    z0 = min(max(z0,0),gd-1); z1 = min(max(z1,0),gd-1);
    y0 = min(max(y0,0),gh-1); y1 = min(max(y1,0),gh-1);
    x0 = min(max(x0,0),gw-1); x1 = min(max(x1,0),gw-1);
    o[0] = (z0*gh+y0)*gw+x0; wt[0] = (1-tz)*(1-ty)*(1-tx);
    o[1] = (z0*gh+y0)*gw+x1; wt[1] = (1-tz)*(1-ty)*tx;
    o[2] = (z0*gh+y1)*gw+x0; wt[2] = (1-tz)*ty*(1-tx);
    o[3] = (z0*gh+y1)*gw+x1; wt[3] = (1-tz)*ty*tx;
    o[4] = (z1*gh+y0)*gw+x0; wt[4] = tz*(1-ty)*(1-tx);
    o[5] = (z1*gh+y0)*gw+x1; wt[5] = tz*(1-ty)*tx;
    o[6] = (z1*gh+y1)*gw+x0; wt[6] = tz*ty*(1-tx);
    o[7] = (z1*gh+y1)*gw+x1; wt[7] = tz*ty*tx;
}

// out = relu((xc + 0.25*(gc + up(p2)+up(p3)+up(p4)))/2)
// pools voxel-major [cell][64] -> vectorized f32x4 gathers, no LDS.
// writes xout fp32 [64][VOL] and xv bf16 [VOL][64]
__global__ __launch_bounds__(256) void k_combine(
        const unsigned short* __restrict__ xc, const float* __restrict__ gc,
        const float* __restrict__ p2, const float* __restrict__ p3,
        const float* __restrict__ p4, float* __restrict__ xout,
        unsigned short* __restrict__ xv){
    int tid = threadIdx.x;
    long v = (long)blockIdx.x*256 + tid;
    int w = v & 127; int h = (v>>7)&63; int d = v>>13;
    int o2[8], o3[8], o4[8];
    float w2_[8], w3_[8], w4_[8];
    tri_setup(d,h,w, 8,8,8,    o2, w2_);
    tri_setup(d,h,w, 16,16,16, o3, w3_);
    tri_setup(d,h,w, 24,32,25, o4, w4_);
#pragma unroll
    for (int half=0; half<2; ++half){
        float res[32];
#pragma unroll
        for (int j=0;j<32;++j) res[j] = gc[half*32+j];
#pragma unroll
        for (int t=0;t<8;++t){
            const float* b2 = p2 + (long)o2[t]*64 + half*32;
#pragma unroll
            for (int q=0;q<8;++q){
                f32x4 x4 = *(const f32x4*)(b2 + q*4);
                res[q*4+0] = fmaf(w2_[t], x4[0], res[q*4+0]);
                res[q*4+1] = fmaf(w2_[t], x4[1], res[q*4+1]);
                res[q*4+2] = fmaf(w2_[t], x4[2], res[q*4+2]);
                res[q*4+3] = fmaf(w2_[t], x4[3], res[q*4+3]);
            }
        }
#pragma unroll
        for (int t=0;t<8;++t){
            const float* b3 = p3 + (long)o3[t]*64 + half*32;
#pragma unroll
            for (int q=0;q<8;++q){
                f32x4 x4 = *(const f32x4*)(b3 + q*4);
                res[q*4+0] = fmaf(w3_[t], x4[0], res[q*4+0]);
                res[q*4+1] = fmaf(w3_[t], x4[1], res[q*4+1]);
                res[q*4+2] = fmaf(w3_[t], x4[2], res[q*4+2]);
                res[q*4+3] = fmaf(w3_[t], x4[3], res[q*4+3]);
            }
        }
#pragma unroll
        for (int t=0;t<8;++t){
            const float* b4 = p4 + (long)o4[t]*64 + half*32;
#pragma unroll
            for (int q=0;q<8;++q){
                f32x4 x4 = *(const f32x4*)(b4 + q*4);
                res[q*4+0] = fmaf(w4_[t], x4[0], res[q*4+0]);
                res[q*4+1] = fmaf(w4_[t], x4[1], res[q*4+1]);
                res[q*4+2] = fmaf(w4_[t], x4[2], res[q*4+2]);
                res[q*4+3] = fmaf(w4_[t], x4[3], res[q*4+3]);
            }
        }
        const u32x4v* xq = (const u32x4v*)(xc + v*64 + half*32);
#pragma unroll
        for (int q=0;q<4;++q){
            u32x4v qv = xq[q];
            unsigned int pk[4];
#pragma unroll
            for (int e=0;e<4;++e){
                int j = q*8 + e*2;
                float r0 = fmaxf((bflo(qv[e]) + 0.25f*res[j])*0.5f, 0.f);
                float r1 = fmaxf((bfhi(qv[e]) + 0.25f*res[j+1])*0.5f, 0.f);
                xout[(long)(half*32+j)*VOL + v]   = r0;
                xout[(long)(half*32+j+1)*VOL + v] = r1;
                pk[e] = (unsigned)f2bf(r0) | ((unsigned)f2bf(r1)<<16);
            }
            u32x4v pq = {pk[0],pk[1],pk[2],pk[3]};
            *(u32x4v*)(xv + v*64 + half*32 + q*8) = pq;
        }
    }
}

// ================= workspace layout (bytes) =================
constexpr long OFF_V0  = 0;                       // bf16 vol: 50,331,648 (also t fp32 27xVOL = 42.5MB)
constexpr long OFF_V1  = 50331648;                // bf16 vol
constexpr long OFF_WA1 = 100663296;               // 221,184
constexpr long OFF_WA2 = OFF_WA1 + 221184;
constexpr long OFF_WC1 = OFF_WA2 + 221184;
constexpr long OFF_NIN = OFF_WC1 + 221184;        // 8,192
constexpr long OFF_MT  = OFF_NIN + 8192;          // 40,960
constexpr long OFF_WT2 = OFF_MT + 40960;          // 4,096 (head taps bf16 [32][64])
constexpr long OFF_WPT = OFF_WT2 + 4096;          // 49,152 (wp1..wp3 fp32 transposed)
constexpr long OFF_GP  = OFF_WPT + 49152;         // 98,304 (384x64 partials)
constexpr long OFF_GC  = OFF_GP + 98304;          // 256
constexpr long OFF_P2  = OFF_GC + 256;            // 131,072
constexpr long OFF_P2C = OFF_P2 + 131072;
constexpr long OFF_P3  = OFF_P2C + 131072;        // 1,048,576
constexpr long OFF_P3C = OFF_P3 + 1048576;
constexpr long OFF_P4  = OFF_P3C + 1048576;       // 4,915,200
constexpr long OFF_P4C = OFF_P4 + 4915200;
// end ~= 113.7 MB

extern "C" void kernel_launch(void* const* d_in, const int* in_sizes, int n_in,
                              void* d_out, int out_size, void* d_ws, size_t ws_size,
                              hipStream_t stream) {
    const float* fvl  = (const float*)d_in[0];
    const float* w_a1 = (const float*)d_in[1];
    const float* w_a2 = (const float*)d_in[2];
    const float* wnin = (const float*)d_in[3];
    const float* w1s  = (const float*)d_in[4];
    const float* w2s  = (const float*)d_in[5];
    const float* wp0  = (const float*)d_in[6];
    const float* wp1  = (const float*)d_in[7];
    const float* wp2  = (const float*)d_in[8];
    const float* wp3  = (const float*)d_in[9];
    const float* wc1  = (const float*)d_in[10];
    const float* wc2  = (const float*)d_in[11];
    const float* bc   = (const float*)d_in[12];

    char* ws = (char*)d_ws;
    unsigned short* V0   = (unsigned short*)(ws + OFF_V0);
    unsigned short* V1   = (unsigned short*)(ws + OFF_V1);
    unsigned short* wa1t = (unsigned short*)(ws + OFF_WA1);
    unsigned short* wa2t = (unsigned short*)(ws + OFF_WA2);
    unsigned short* wc1t = (unsigned short*)(ws + OFF_WC1);
    unsigned short* nint = (unsigned short*)(ws + OFF_NIN);
    unsigned short* Mt   = (unsigned short*)(ws + OFF_MT);
    unsigned short* wt2  = (unsigned short*)(ws + OFF_WT2);
    float* wpt  = (float*)(ws + OFF_WPT);
    float* gp   = (float*)(ws + OFF_GP);
    float* gc   = (float*)(ws + OFF_GC);
    float* p2   = (float*)(ws + OFF_P2);
    float* p2c  = (float*)(ws + OFF_P2C);
    float* p3   = (float*)(ws + OFF_P3);
    float* p3c  = (float*)(ws + OFF_P3C);
    float* p4   = (float*)(ws + OFF_P4);
    float* p4c  = (float*)(ws + OFF_P4C);

    float* Xout = (float*)d_out;                       // [64][VOL] fp32
    float* Cout = Xout + (long)NC*VOL;                 // [VOL] fp32
    unsigned short* V2 = (unsigned short*)d_out;       // transient bf16 vol inside x region
    float* Tbuf = (float*)(ws + OFF_V0);               // head t buffer, reuses V0 after stage E conv

    const int GB = VOL/256;    // 1536 blocks for MFMA volume kernels

    // --- prep ---
    k_wprep3<<<(27*64*64+255)/256,256,0,stream>>>(w_a1, wa1t);
    k_wprep3<<<(27*64*64+255)/256,256,0,stream>>>(w_a2, wa2t);
    k_wprep3<<<(27*64*64+255)/256,256,0,stream>>>(wc1, wc1t);
    k_wprep1<<<16,256,0,stream>>>(wnin, nint);
    k_wprep2<<<8,256,0,stream>>>(wc2, wt2);
    k_fuse_res<<<80,256,0,stream>>>(w1s, w2s, Mt);
    k_transpose1<<<16,256,0,stream>>>(wp1, wpt + 0*4096);
    k_transpose1<<<16,256,0,stream>>>(wp2, wpt + 1*4096);
    k_transpose1<<<16,256,0,stream>>>(wp3, wpt + 2*4096);
    k_tobf16v<<<VOL/64,256,0,stream>>>(fvl, V0);

    // --- stage A: V1 = conv3(V0, wa1) ---
    k_conv3m<false,false><<<GB,256,0,stream>>>(V0, wa1t, nullptr, nullptr, V1);
    // --- stage B: V2 = conv3(V1, wa2) + conv1(V0, nin) ---
    k_conv3m<true,false><<<GB,256,0,stream>>>(V1, wa2t, V0, nint, V2);

    // --- stage C: 5x fused residual 1x1 (relu), ping-pong V2 <-> V1, ends in V1 ---
    unsigned short* cur = V2; unsigned short* nxt = V1;
    for (int i=0;i<5;++i){
        k_conv1m<<<GB,256,0,stream>>>(cur, Mt + i*4096, nxt);
        unsigned short* t = cur; cur = nxt; nxt = t;
    }
    // cur == V1

    // --- stage D: pool pyramid ---
    k_gpool<<<384,256,0,stream>>>(cur, gp);
    k_gfin<<<1,64,0,stream>>>(gp, wp0, gc);

    k_avgpool<<<(64*512+255)/256,256,0,stream>>>(cur, p2, 8,8,8,   6,8,16);
    k_conv1<<<2,256,0,stream>>>(p2, wpt + 0*4096, p2c, 512);

    k_avgpool<<<(64*4096+255)/256,256,0,stream>>>(cur, p3, 16,16,16, 3,4,8);
    k_conv1<<<16,256,0,stream>>>(p3, wpt + 1*4096, p3c, 4096);

    k_avgpool<<<(64*19200+255)/256,256,0,stream>>>(cur, p4, 24,32,25, 2,2,5);
    k_conv1<<<75,256,0,stream>>>(p4, wpt + 2*4096, p4c, 19200);

    // --- combine: write x (fp32, d_out) + bf16 copy into V0 region ---
    k_combine<<<GB,256,0,stream>>>(cur, gc, p2c, p3c, p4c, Xout, V0);

    // --- head: V1 = relu(conv3(x, wc1)); t = V1 @ wc2-taps; Cout = scatter-sum(t) + bc ---
    k_conv3m<false,true><<<GB,256,0,stream>>>(V0, wc1t, nullptr, nullptr, V1);
    k_headt<<<GB,256,0,stream>>>(V1, wt2, Tbuf);   // V0 region is free now
    k_heads<<<GB,256,0,stream>>>(Tbuf, bc, Cout);
}

// Round 6
// 1569.562 us; speedup vs baseline: 1.3127x; 1.0148x over previous
//
#include <hip/hip_runtime.h>
#include <math.h>

#define DD 48
#define HH 64
#define WW 128
#define VOL (DD*HH*WW)   // 393216
#define NC 64

typedef __attribute__((ext_vector_type(8))) short bf16x8;
typedef __attribute__((ext_vector_type(4))) float f32x4;
typedef __attribute__((ext_vector_type(4))) unsigned int u32x4v;
typedef __attribute__((ext_vector_type(2))) unsigned int u32x2v;

__device__ __forceinline__ float bflo(unsigned int u){
    union { unsigned int i; float f; } x; x.i = u<<16; return x.f; }
__device__ __forceinline__ float bfhi(unsigned int u){
    union { unsigned int i; float f; } x; x.i = u & 0xffff0000u; return x.f; }
__device__ __forceinline__ float bf2f(unsigned short u){
    union { unsigned int i; float f; } x; x.i = ((unsigned int)u)<<16; return x.f; }
__device__ __forceinline__ unsigned short f2bf(float f){
    union { float f; unsigned int i; } x; x.f = f;
    unsigned int i = x.i;
    return (unsigned short)((i + 0x7fffu + ((i>>16)&1u)) >> 16);  // RNE
}

// ================= weight prep =================

// src [co=64][ci=64][k=27] fp32 -> dst [k=27][co=64][ci=64] bf16
__global__ void k_wprep3(const float* __restrict__ src, unsigned short* __restrict__ dst){
    int idx = blockIdx.x*256 + threadIdx.x;
    if (idx >= 27*64*64) return;
    int ci = idx & 63; int t = idx >> 6; int co = t & 63; int k = t >> 6;
    dst[idx] = f2bf(src[(co*64+ci)*27 + k]);
}

// src [co][ci] fp32 -> dst [co][ci] bf16 (elementwise convert)
__global__ void k_wprep1(const float* __restrict__ src, unsigned short* __restrict__ dst){
    int idx = blockIdx.x*256 + threadIdx.x;
    if (idx >= 4096) return;
    dst[idx] = f2bf(src[idx]);
}

// wc2 [co=64][tap=27] fp32 -> dst [taprow=32][co=64] bf16 (taps >=27 zero)
__global__ void k_wprep2(const float* __restrict__ src, unsigned short* __restrict__ dst){
    int idx = blockIdx.x*256 + threadIdx.x;
    if (idx >= 32*64) return;
    int co = idx & 63; int row = idx >> 6;
    float v = (row < 27) ? src[co*27 + row] : 0.f;
    dst[row*64 + co] = f2bf(v);
}

// M_i = W1_i + W2_i @ W1_i, output bf16 [i][co][ci]
__global__ void k_fuse_res(const float* __restrict__ w1, const float* __restrict__ w2,
                           unsigned short* __restrict__ mt){
    int idx = blockIdx.x*256 + threadIdx.x;
    if (idx >= 5*4096) return;
    int i = idx >> 12; int r = idx & 4095;
    int co = r >> 6; int ci = r & 63;
    const float* W1 = w1 + i*4096;
    const float* W2 = w2 + i*4096;
    float m = W1[co*64+ci];
    for (int k=0;k<64;++k) m += W2[co*64+k]*W1[k*64+ci];
    mt[idx] = f2bf(m);
}

// dst[ci*64+co] = src[co*64+ci]  (fp32, for pool 1x1 convs)
__global__ void k_transpose1(const float* __restrict__ src, float* __restrict__ dst){
    int idx = blockIdx.x*256 + threadIdx.x;
    if (idx >= 4096) return;
    int ci = idx >> 6; int co = idx & 63;
    dst[idx] = src[co*64+ci];
}

// ============ fvl [64][VOL] fp32 -> [VOL][64] bf16 (LDS transpose) ============
__global__ __launch_bounds__(256) void k_tobf16v(const float* __restrict__ src,
                                                 unsigned short* __restrict__ dst){
    __shared__ unsigned short lds[64*66];
    int tid = threadIdx.x;
    long vbase = (long)blockIdx.x*64;
    int v = tid & 63;
    int cg = tid >> 6;
#pragma unroll
    for (int k=0;k<16;++k){
        int ci = cg*16 + k;
        lds[v*66 + ci] = f2bf(src[(long)ci*VOL + vbase + v]);
    }
    __syncthreads();
#pragma unroll
    for (int it=0; it<2; ++it){
        int chunk = it*256 + tid;       // 512 chunks = 64v x 8 groups
        int vv = chunk >> 3, gp = chunk & 7;
        const unsigned short* s = lds + vv*66 + gp*8;
        unsigned int w0 = (unsigned)s[0] | ((unsigned)s[1]<<16);
        unsigned int w1 = (unsigned)s[2] | ((unsigned)s[3]<<16);
        unsigned int w2 = (unsigned)s[4] | ((unsigned)s[5]<<16);
        unsigned int w3 = (unsigned)s[6] | ((unsigned)s[7]<<16);
        u32x4v q = {w0,w1,w2,w3};
        *(u32x4v*)(dst + (vbase+vv)*64 + gp*8) = q;
    }
}

// ============ MFMA conv3x3x3: XCD-swizzled grid + 1-deep software pipeline ============
// in/out [VOL][64] bf16, wt [27][co][ci] bf16
// wave: 64co x 64vox; block: 4 waves = 256 voxels (2 W-rows)
template<bool AUX, bool RELU>
__global__ __launch_bounds__(256,3) void k_conv3m(
    const unsigned short* __restrict__ in, const unsigned short* __restrict__ wt,
    const unsigned short* __restrict__ aux, const unsigned short* __restrict__ auxw,
    unsigned short* __restrict__ out)
{
    const int lane = threadIdx.x & 63;
    const int wave = threadIdx.x >> 6;
    const int ll = lane & 15;
    const int kg = lane >> 4;
    // XCD-aware swizzle: 1536 blocks, 8 XCDs, 192 consecutive work-ids per XCD
    // -> each XCD owns 6 contiguous d-planes; halo reuse stays in its L2.
    const int bid = blockIdx.x;
    const int wid = ((bid & 7) * 192) + (bid >> 3);
    const int vb = wid*256 + wave*64;
    const int h = (vb >> 7) & 63;
    const int d = vb >> 13;

    f32x4 acc[4][4];
#pragma unroll
    for (int a=0;a<4;++a)
#pragma unroll
        for (int b=0;b<4;++b) acc[a][b] = (f32x4){0.f,0.f,0.f,0.f};
    const bf16x8 zero = {0,0,0,0,0,0,0,0};

    // group g in [0,54): tap = g>>1, khalf = g&1
    auto ldA = [&](bf16x8* dst, int g){
        const int tap = g >> 1; const int ko = (g & 1)*32 + kg*8;
        const unsigned short* wk = wt + tap*4096 + ko;
#pragma unroll
        for (int t=0;t<4;++t) dst[t] = *(const bf16x8*)(wk + (t*16+ll)*64);
    };
    auto ldB = [&](bf16x8* dst, int g){
        const int tap = g >> 1; const int ko = (g & 1)*32 + kg*8;
        const int kd = tap/9, kh = (tap/3)%3, kw = tap%3;
        const long dv = (long)((kd-1)*8192 + (kh-1)*128 + (kw-1));
        const bool okdh = ((unsigned)(d+kd-1) < 48u) && ((unsigned)(h+kh-1) < 64u);
#pragma unroll
        for (int vt=0; vt<4; ++vt){
            const int vx = vb + vt*16 + ll;
            const bool ok = okdh && ((unsigned)((vx & 127) + kw - 1) < 128u);
            const long va = ok ? ((long)vx + dv) : (long)vx;   // always in-bounds
            bf16x8 v = *(const bf16x8*)(in + va*64 + ko);
            dst[vt] = ok ? v : zero;                            // cndmask, no branch
        }
    };

    bf16x8 A[2][4], B[2][4];
    ldA(A[0], 0); ldB(B[0], 0);
#pragma unroll
    for (int g=0; g<54; ++g){
        const int cb = g & 1, nb = cb ^ 1;
        if (g < 53){ ldA(A[nb], g+1); ldB(B[nb], g+1); }   // prefetch next group
#pragma unroll
        for (int vt=0; vt<4; ++vt)
#pragma unroll
            for (int t=0; t<4; ++t)
                acc[t][vt] = __builtin_amdgcn_mfma_f32_16x16x32_bf16(A[cb][t], B[cb][vt], acc[t][vt], 0,0,0);
    }

    if (AUX){
        bf16x8 Aa[2][4], Ba[2][4];
#pragma unroll
        for (int half=0; half<2; ++half){
            const int ko = half*32 + kg*8;
#pragma unroll
            for (int t=0;t<4;++t)
                Aa[half][t] = *(const bf16x8*)(auxw + (t*16+ll)*64 + ko);
#pragma unroll
            for (int vt=0; vt<4; ++vt)
                Ba[half][vt] = *(const bf16x8*)(aux + (long)(vb+vt*16+ll)*64 + ko);
        }
#pragma unroll
        for (int half=0; half<2; ++half)
#pragma unroll
            for (int vt=0; vt<4; ++vt)
#pragma unroll
                for (int t=0;t<4;++t)
                    acc[t][vt] = __builtin_amdgcn_mfma_f32_16x16x32_bf16(Aa[half][t], Ba[half][vt], acc[t][vt], 0,0,0);
    }

#pragma unroll
    for (int vt=0; vt<4; ++vt){
        int vx = vb + vt*16 + ll;
        unsigned short* op = out + (long)vx*64 + kg*4;
#pragma unroll
        for (int t=0;t<4;++t){
            float r0 = acc[t][vt][0], r1 = acc[t][vt][1], r2 = acc[t][vt][2], r3 = acc[t][vt][3];
            if (RELU){ r0=fmaxf(r0,0.f); r1=fmaxf(r1,0.f); r2=fmaxf(r2,0.f); r3=fmaxf(r3,0.f); }
            unsigned int lo = (unsigned)f2bf(r0) | ((unsigned)f2bf(r1)<<16);
            unsigned int hi = (unsigned)f2bf(r2) | ((unsigned)f2bf(r3)<<16);
            u32x2v q = {lo, hi};
            *(u32x2v*)(op + t*16) = q;
        }
    }
}

// ============ MFMA 1x1 conv (fused residual), relu; wt [co][ci] bf16 ============
// All 16 loads issued up-front, then 32 MFMAs.
__global__ __launch_bounds__(256,3) void k_conv1m(const unsigned short* __restrict__ in,
        const unsigned short* __restrict__ wt, unsigned short* __restrict__ out){
    const int lane = threadIdx.x & 63;
    const int wave = threadIdx.x >> 6;
    const int ll = lane & 15;
    const int kg = lane >> 4;
    const int vb = blockIdx.x*256 + wave*64;

    bf16x8 A[2][4], B[2][4];
#pragma unroll
    for (int half=0; half<2; ++half){
        const int ko = half*32 + kg*8;
#pragma unroll
        for (int t=0;t<4;++t)
            A[half][t] = *(const bf16x8*)(wt + (t*16+ll)*64 + ko);
#pragma unroll
        for (int vt=0; vt<4; ++vt)
            B[half][vt] = *(const bf16x8*)(in + (long)(vb+vt*16+ll)*64 + ko);
    }

    f32x4 acc[4][4];
#pragma unroll
    for (int a=0;a<4;++a)
#pragma unroll
        for (int b=0;b<4;++b) acc[a][b] = (f32x4){0.f,0.f,0.f,0.f};

#pragma unroll
    for (int half=0; half<2; ++half)
#pragma unroll
        for (int vt=0; vt<4; ++vt)
#pragma unroll
            for (int t=0;t<4;++t)
                acc[t][vt] = __builtin_amdgcn_mfma_f32_16x16x32_bf16(A[half][t], B[half][vt], acc[t][vt], 0,0,0);

#pragma unroll
    for (int vt=0; vt<4; ++vt){
        int vx = vb + vt*16 + ll;
        unsigned short* op = out + (long)vx*64 + kg*4;
#pragma unroll
        for (int t=0;t<4;++t){
            float r0 = fmaxf(acc[t][vt][0],0.f), r1 = fmaxf(acc[t][vt][1],0.f);
            float r2 = fmaxf(acc[t][vt][2],0.f), r3 = fmaxf(acc[t][vt][3],0.f);
            unsigned int lo = (unsigned)f2bf(r0) | ((unsigned)f2bf(r1)<<16);
            unsigned int hi = (unsigned)f2bf(r2) | ((unsigned)f2bf(r3)<<16);
            u32x2v q = {lo, hi};
            *(u32x2v*)(op + t*16) = q;
        }
    }
}

// ============ head stage 1: t[tap][v] = sum_co V1[v][co]*wc2[co][tap]  (MFMA) ============
// wt2 [32 taprows][64 co] bf16; out t fp32 [27][VOL]
__global__ __launch_bounds__(256) void k_headt(const unsigned short* __restrict__ in,
        const unsigned short* __restrict__ wt2, float* __restrict__ t){
    const int lane = threadIdx.x & 63;
    const int wave = threadIdx.x >> 6;
    const int ll = lane & 15;
    const int kg = lane >> 4;
    const int vb = blockIdx.x*256 + wave*64;

    f32x4 acc[2][4];
#pragma unroll
    for (int a=0;a<2;++a)
#pragma unroll
        for (int b=0;b<4;++b) acc[a][b] = (f32x4){0.f,0.f,0.f,0.f};

#pragma unroll
    for (int khalf=0; khalf<2; ++khalf){
        const int ko = khalf*32 + kg*8;
        bf16x8 afr[2];
#pragma unroll
        for (int tl=0;tl<2;++tl)
            afr[tl] = *(const bf16x8*)(wt2 + (tl*16+ll)*64 + ko);
#pragma unroll
        for (int vt=0; vt<4; ++vt){
            bf16x8 bfr = *(const bf16x8*)(in + (long)(vb+vt*16+ll)*64 + ko);
#pragma unroll
            for (int tl=0;tl<2;++tl)
                acc[tl][vt] = __builtin_amdgcn_mfma_f32_16x16x32_bf16(afr[tl], bfr, acc[tl][vt], 0,0,0);
        }
    }
#pragma unroll
    for (int vt=0; vt<4; ++vt){
        int vx = vb + vt*16 + ll;
#pragma unroll
        for (int tl=0;tl<2;++tl){
#pragma unroll
            for (int r=0;r<4;++r){
                int tap = tl*16 + kg*4 + r;
                if (tap < 27) t[(long)tap*VOL + vx] = acc[tl][vt][r];
            }
        }
    }
}

// ============ head stage 2: out[v] = bias + sum_tap t[tap][v+dv(tap)] ============
__global__ __launch_bounds__(256) void k_heads(const float* __restrict__ t,
        const float* __restrict__ bias, float* __restrict__ out){
    int v = blockIdx.x*256 + threadIdx.x;
    int ww = v & 127; int h = (v>>7)&63; int d = v>>13;
    float s = bias[0];
#pragma unroll
    for (int kd=0;kd<3;++kd){
#pragma unroll
      for (int kh=0;kh<3;++kh){
#pragma unroll
        for (int kw=0;kw<3;++kw){
            const int tap = (kd*3+kh)*3+kw;
            const long dv = (long)((kd-1)*8192 + (kh-1)*128 + (kw-1));
            bool ok = ((unsigned)(d+kd-1)<48u) && ((unsigned)(h+kh-1)<64u) && ((unsigned)(ww+kw-1)<128u);
            long va = ok ? ((long)v + dv) : (long)v;
            float x = t[(long)tap*VOL + va];
            s += ok ? x : 0.f;
        }
      }
    }
    out[v] = s;
}

// ============ global pool partials: 384 blocks x 1024 vox, part[b][64] ============
__global__ __launch_bounds__(256) void k_gpool(const unsigned short* __restrict__ in,
                                               float* __restrict__ part){
    __shared__ float sm[32][64];
    int cg = threadIdx.x & 7;
    int r  = threadIdx.x >> 3;
    long vb = (long)blockIdx.x*1024;
    float a[8];
#pragma unroll
    for (int j=0;j<8;++j) a[j]=0.f;
    for (int v = r; v < 1024; v += 32){
        u32x4v q = *(const u32x4v*)(in + (vb+v)*64 + cg*8);
#pragma unroll
        for (int e=0;e<4;++e){
            a[e*2]   += bflo(q[e]);
            a[e*2+1] += bfhi(q[e]);
        }
    }
#pragma unroll
    for (int j=0;j<8;++j) sm[r][cg*8+j] = a[j];
    __syncthreads();
    if (threadIdx.x < 64){
        float s=0.f;
        for (int rr=0;rr<32;++rr) s += sm[rr][threadIdx.x];
        part[blockIdx.x*64 + threadIdx.x] = s;
    }
}

// reduce partials -> g, then gc[co] = sum_ci wp0[co][ci] * g[ci] / VOL
__global__ void k_gfin(const float* __restrict__ part, const float* __restrict__ wp0,
                       float* __restrict__ gc){
    __shared__ float sg[64];
    int t = threadIdx.x;
    if (t < 64){
        float s=0.f;
        for (int b=0;b<384;++b) s += part[b*64 + t];
        sg[t] = s * (1.0f/(float)VOL);
    }
    __syncthreads();
    if (t < 64){
        float s=0.f;
        for (int ci=0;ci<64;++ci) s += wp0[t*64+ci]*sg[ci];
        gc[t] = s;
    }
}

// ============ avg pool (VALID, stride=ksize), bf16 vox-major in, fp32 [c][cells] out ============
__global__ void k_avgpool(const unsigned short* __restrict__ in, float* __restrict__ out,
                          int od,int oh,int ow,int kd,int kh,int kw){
    int ovol = od*oh*ow;
    int idx = blockIdx.x*256 + threadIdx.x;
    if (idx >= 64*ovol) return;
    int c = idx & 63; int cell = idx >> 6;
    int z = cell/(oh*ow); int rem = cell - z*(oh*ow); int y = rem/ow; int x = rem - y*ow;
    float s = 0.f;
    for (int a=0;a<kd;++a)
        for (int b=0;b<kh;++b)
            for (int e=0;e<kw;++e){
                long v = ((long)(z*kd+a)*64 + (y*kh+b))*128 + (x*kw+e);
                s += bf2f(in[v*64 + c]);
            }
    out[c*ovol + cell] = s / (float)(kd*kh*kw);
}

// ============ 1x1 conv fp32 on pooled grids; wt [ci][co], OUT voxel-major [cell][64] ============
__global__ void k_conv1(const float* __restrict__ in, const float* __restrict__ wt,
                        float* __restrict__ out, int vol){
    int v = blockIdx.x*256 + threadIdx.x;
    if (v >= vol) return;
    float acc[64];
#pragma unroll
    for (int i=0;i<64;++i) acc[i]=0.f;
    for (int ci=0; ci<64; ++ci){
        float xv = in[ci*vol + v];
        const float* wr = wt + ci*64;
#pragma unroll
        for (int co=0; co<64; ++co) acc[co] = fmaf(wr[co], xv, acc[co]);
    }
    float* op = out + (long)v*64;
#pragma unroll
    for (int q=0;q<16;++q){
        f32x4 t = {acc[q*4], acc[q*4+1], acc[q*4+2], acc[q*4+3]};
        *(f32x4*)(op + q*4) = t;
    }
}

// ============ trilinear gather ============
__device__ __forceinline__ void tri_setup(int d,int h,int w,int gd,int gh,int gw,
                                          int* o, float* wt){
    float fz = (d+0.5f)*((float)gd/(float)DD) - 0.5f;
    float fy = (h+0.5f)*((float)gh/(float)HH) - 0.5f;
    float fx = (w+0.5f)*((float)gw/(float)WW) - 0.5f;
    float z0f = floorf(fz), y0f = floorf(fy), x0f = floorf(fx);
    float tz = fz - z0f, ty = fy - y0f, tx = fx - x0f;
    int z0 = (int)z0f, y0 = (int)y0f, x0 = (int)x0f;
    int z1 = z0+1, y1 = y0+1, x1 = x0+1;
    z0 = min(max(z0,0),gd-1); z1 = min(max(z1,0),gd-1);
    y0 = min(max(y0,0),gh-1); y1 = min(max(y1,0),gh-1);
    x0 = min(max(x0,0),gw-1); x1 = min(max(x1,0),gw-1);
    o[0] = (z0*gh+y0)*gw+x0; wt[0] = (1-tz)*(1-ty)*(1-tx);
    o[1] = (z0*gh+y0)*gw+x1; wt[1] = (1-tz)*(1-ty)*tx;
    o[2] = (z0*gh+y1)*gw+x0; wt[2] = (1-tz)*ty*(1-tx);
    o[3] = (z0*gh+y1)*gw+x1; wt[3] = (1-tz)*ty*tx;
    o[4] = (z1*gh+y0)*gw+x0; wt[4] = tz*(1-ty)*(1-tx);
    o[5] = (z1*gh+y0)*gw+x1; wt[5] = tz*(1-ty)*tx;
    o[6] = (z1*gh+y1)*gw+x0; wt[6] = tz*ty*(1-tx);
    o[7] = (z1*gh+y1)*gw+x1; wt[7] = tz*ty*tx;
}

// out = relu((xc + 0.25*(gc + up(p2)+up(p3)+up(p4)))/2)
// pools voxel-major [cell][64] -> vectorized f32x4 gathers, no LDS.
// writes xout fp32 [64][VOL] and xv bf16 [VOL][64]
__global__ __launch_bounds__(256) void k_combine(
        const unsigned short* __restrict__ xc, const float* __restrict__ gc,
        const float* __restrict__ p2, const float* __restrict__ p3,
        const float* __restrict__ p4, float* __restrict__ xout,
        unsigned short* __restrict__ xv){
    int tid = threadIdx.x;
    long v = (long)blockIdx.x*256 + tid;
    int w = v & 127; int h = (v>>7)&63; int d = v>>13;
    int o2[8], o3[8], o4[8];
    float w2_[8], w3_[8], w4_[8];
    tri_setup(d,h,w, 8,8,8,    o2, w2_);
    tri_setup(d,h,w, 16,16,16, o3, w3_);
    tri_setup(d,h,w, 24,32,25, o4, w4_);
#pragma unroll
    for (int half=0; half<2; ++half){
        float res[32];
#pragma unroll
        for (int j=0;j<32;++j) res[j] = gc[half*32+j];
#pragma unroll
        for (int t=0;t<8;++t){
            const float* b2 = p2 + (long)o2[t]*64 + half*32;
#pragma unroll
            for (int q=0;q<8;++q){
                f32x4 x4 = *(const f32x4*)(b2 + q*4);
                res[q*4+0] = fmaf(w2_[t], x4[0], res[q*4+0]);
                res[q*4+1] = fmaf(w2_[t], x4[1], res[q*4+1]);
                res[q*4+2] = fmaf(w2_[t], x4[2], res[q*4+2]);
                res[q*4+3] = fmaf(w2_[t], x4[3], res[q*4+3]);
            }
        }
#pragma unroll
        for (int t=0;t<8;++t){
            const float* b3 = p3 + (long)o3[t]*64 + half*32;
#pragma unroll
            for (int q=0;q<8;++q){
                f32x4 x4 = *(const f32x4*)(b3 + q*4);
                res[q*4+0] = fmaf(w3_[t], x4[0], res[q*4+0]);
                res[q*4+1] = fmaf(w3_[t], x4[1], res[q*4+1]);
                res[q*4+2] = fmaf(w3_[t], x4[2], res[q*4+2]);
                res[q*4+3] = fmaf(w3_[t], x4[3], res[q*4+3]);
            }
        }
#pragma unroll
        for (int t=0;t<8;++t){
            const float* b4 = p4 + (long)o4[t]*64 + half*32;
#pragma unroll
            for (int q=0;q<8;++q){
                f32x4 x4 = *(const f32x4*)(b4 + q*4);
                res[q*4+0] = fmaf(w4_[t], x4[0], res[q*4+0]);
                res[q*4+1] = fmaf(w4_[t], x4[1], res[q*4+1]);
                res[q*4+2] = fmaf(w4_[t], x4[2], res[q*4+2]);
                res[q*4+3] = fmaf(w4_[t], x4[3], res[q*4+3]);
            }
        }
        const u32x4v* xq = (const u32x4v*)(xc + v*64 + half*32);
#pragma unroll
        for (int q=0;q<4;++q){
            u32x4v qv = xq[q];
            unsigned int pk[4];
#pragma unroll
            for (int e=0;e<4;++e){
                int j = q*8 + e*2;
                float r0 = fmaxf((bflo(qv[e]) + 0.25f*res[j])*0.5f, 0.f);
                float r1 = fmaxf((bfhi(qv[e]) + 0.25f*res[j+1])*0.5f, 0.f);
                xout[(long)(half*32+j)*VOL + v]   = r0;
                xout[(long)(half*32+j+1)*VOL + v] = r1;
                pk[e] = (unsigned)f2bf(r0) | ((unsigned)f2bf(r1)<<16);
            }
            u32x4v pq = {pk[0],pk[1],pk[2],pk[3]};
            *(u32x4v*)(xv + v*64 + half*32 + q*8) = pq;
        }
    }
}

// ================= workspace layout (bytes) =================
constexpr long OFF_V0  = 0;                       // bf16 vol: 50,331,648 (also t fp32 27xVOL = 42.5MB)
constexpr long OFF_V1  = 50331648;                // bf16 vol
constexpr long OFF_WA1 = 100663296;               // 221,184
constexpr long OFF_WA2 = OFF_WA1 + 221184;
constexpr long OFF_WC1 = OFF_WA2 + 221184;
constexpr long OFF_NIN = OFF_WC1 + 221184;        // 8,192
constexpr long OFF_MT  = OFF_NIN + 8192;          // 40,960
constexpr long OFF_WT2 = OFF_MT + 40960;          // 4,096 (head taps bf16 [32][64])
constexpr long OFF_WPT = OFF_WT2 + 4096;          // 49,152 (wp1..wp3 fp32 transposed)
constexpr long OFF_GP  = OFF_WPT + 49152;         // 98,304 (384x64 partials)
constexpr long OFF_GC  = OFF_GP + 98304;          // 256
constexpr long OFF_P2  = OFF_GC + 256;            // 131,072
constexpr long OFF_P2C = OFF_P2 + 131072;
constexpr long OFF_P3  = OFF_P2C + 131072;        // 1,048,576
constexpr long OFF_P3C = OFF_P3 + 1048576;
constexpr long OFF_P4  = OFF_P3C + 1048576;       // 4,915,200
constexpr long OFF_P4C = OFF_P4 + 4915200;
// end ~= 113.7 MB

extern "C" void kernel_launch(void* const* d_in, const int* in_sizes, int n_in,
                              void* d_out, int out_size, void* d_ws, size_t ws_size,
                              hipStream_t stream) {
    const float* fvl  = (const float*)d_in[0];
    const float* w_a1 = (const float*)d_in[1];
    const float* w_a2 = (const float*)d_in[2];
    const float* wnin = (const float*)d_in[3];
    const float* w1s  = (const float*)d_in[4];
    const float* w2s  = (const float*)d_in[5];
    const float* wp0  = (const float*)d_in[6];
    const float* wp1  = (const float*)d_in[7];
    const float* wp2  = (const float*)d_in[8];
    const float* wp3  = (const float*)d_in[9];
    const float* wc1  = (const float*)d_in[10];
    const float* wc2  = (const float*)d_in[11];
    const float* bc   = (const float*)d_in[12];

    char* ws = (char*)d_ws;
    unsigned short* V0   = (unsigned short*)(ws + OFF_V0);
    unsigned short* V1   = (unsigned short*)(ws + OFF_V1);
    unsigned short* wa1t = (unsigned short*)(ws + OFF_WA1);
    unsigned short* wa2t = (unsigned short*)(ws + OFF_WA2);
    unsigned short* wc1t = (unsigned short*)(ws + OFF_WC1);
    unsigned short* nint = (unsigned short*)(ws + OFF_NIN);
    unsigned short* Mt   = (unsigned short*)(ws + OFF_MT);
    unsigned short* wt2  = (unsigned short*)(ws + OFF_WT2);
    float* wpt  = (float*)(ws + OFF_WPT);
    float* gp   = (float*)(ws + OFF_GP);
    float* gc   = (float*)(ws + OFF_GC);
    float* p2   = (float*)(ws + OFF_P2);
    float* p2c  = (float*)(ws + OFF_P2C);
    float* p3   = (float*)(ws + OFF_P3);
    float* p3c  = (float*)(ws + OFF_P3C);
    float* p4   = (float*)(ws + OFF_P4);
    float* p4c  = (float*)(ws + OFF_P4C);

    float* Xout = (float*)d_out;                       // [64][VOL] fp32
    float* Cout = Xout + (long)NC*VOL;                 // [VOL] fp32
    unsigned short* V2 = (unsigned short*)d_out;       // transient bf16 vol inside x region
    float* Tbuf = (float*)(ws + OFF_V0);               // head t buffer, reuses V0 after stage E conv

    const int GB = VOL/256;    // 1536 blocks for MFMA volume kernels

    // --- prep ---
    k_wprep3<<<(27*64*64+255)/256,256,0,stream>>>(w_a1, wa1t);
    k_wprep3<<<(27*64*64+255)/256,256,0,stream>>>(w_a2, wa2t);
    k_wprep3<<<(27*64*64+255)/256,256,0,stream>>>(wc1, wc1t);
    k_wprep1<<<16,256,0,stream>>>(wnin, nint);
    k_wprep2<<<8,256,0,stream>>>(wc2, wt2);
    k_fuse_res<<<80,256,0,stream>>>(w1s, w2s, Mt);
    k_transpose1<<<16,256,0,stream>>>(wp1, wpt + 0*4096);
    k_transpose1<<<16,256,0,stream>>>(wp2, wpt + 1*4096);
    k_transpose1<<<16,256,0,stream>>>(wp3, wpt + 2*4096);
    k_tobf16v<<<VOL/64,256,0,stream>>>(fvl, V0);

    // --- stage A: V1 = conv3(V0, wa1) ---
    k_conv3m<false,false><<<GB,256,0,stream>>>(V0, wa1t, nullptr, nullptr, V1);
    // --- stage B: V2 = conv3(V1, wa2) + conv1(V0, nin) ---
    k_conv3m<true,false><<<GB,256,0,stream>>>(V1, wa2t, V0, nint, V2);

    // --- stage C: 5x fused residual 1x1 (relu), ping-pong V2 <-> V1, ends in V1 ---
    unsigned short* cur = V2; unsigned short* nxt = V1;
    for (int i=0;i<5;++i){
        k_conv1m<<<GB,256,0,stream>>>(cur, Mt + i*4096, nxt);
        unsigned short* t = cur; cur = nxt; nxt = t;
    }
    // cur == V1

    // --- stage D: pool pyramid ---
    k_gpool<<<384,256,0,stream>>>(cur, gp);
    k_gfin<<<1,64,0,stream>>>(gp, wp0, gc);

    k_avgpool<<<(64*512+255)/256,256,0,stream>>>(cur, p2, 8,8,8,   6,8,16);
    k_conv1<<<2,256,0,stream>>>(p2, wpt + 0*4096, p2c, 512);

    k_avgpool<<<(64*4096+255)/256,256,0,stream>>>(cur, p3, 16,16,16, 3,4,8);
    k_conv1<<<16,256,0,stream>>>(p3, wpt + 1*4096, p3c, 4096);

    k_avgpool<<<(64*19200+255)/256,256,0,stream>>>(cur, p4, 24,32,25, 2,2,5);
    k_conv1<<<75,256,0,stream>>>(p4, wpt + 2*4096, p4c, 19200);

    // --- combine: write x (fp32, d_out) + bf16 copy into V0 region ---
    k_combine<<<GB,256,0,stream>>>(cur, gc, p2c, p3c, p4c, Xout, V0);

    // --- head: V1 = relu(conv3(x, wc1)); t = V1 @ wc2-taps; Cout = scatter-sum(t) + bc ---
    k_conv3m<false,true><<<GB,256,0,stream>>>(V0, wc1t, nullptr, nullptr, V1);
    k_headt<<<GB,256,0,stream>>>(V1, wt2, Tbuf);   // V0 region is free now
    k_heads<<<GB,256,0,stream>>>(Tbuf, bc, Cout);
}